// Round 10
// baseline (264.895 us; speedup 1.0000x reference)
//
#include <hip/hip_runtime.h>
#include <stdint.h>

#define HW 512
#define IMG (HW*HW)
#define CNUM_ 6

#define TILE 32
#define HALO 12
#define ST 56            // staged tile edge
#define SSTR 57          // LDS row stride (floats)
#define NT 256
#define RCAP 128         // ring list cap (structural max ~104)

typedef float f2 __attribute__((ext_vector_type(2)));

// per-class list caps/offsets: cap(c) = 640-64c, off(c) = c*(672-32c)
#define LTOT 2880

// ws float layout:
// [0..511]   per-block minmax partials (min at 2k, max at 2k+1)
// [512..527] mn  [528..543] sc  [544..559] inv
// [RECBASE + r*REC_F]  r=(b*6+cls):
//   [0..74] weff (l*25+e), [75..77] beff, [78..95] bezier Horner coeffs (l*6+q)
// [VARBASE + (r*9+kind)*3*VAR_F + l*VAR_F]: border-variant [0..24] w, [25] bias
#define OFF_MN 512
#define OFF_SC 528
#define OFF_INV 544
#define RECBASE 1024
#define REC_F 96
#define VARBASE (RECBASE + 96*REC_F)
#define VAR_F 27

__global__ __launch_bounds__(256) void k_minmax(const float4* __restrict__ x, float* __restrict__ wsf){
    int blk = blockIdx.x;            // blk = b*16 + chunk
    int base4 = blk * 4096;
    float vmin = 1e30f, vmax = -1e30f;
#pragma unroll
    for (int k = 0; k < 16; k++){
        float4 v = x[base4 + k*256 + threadIdx.x];
        vmin = fminf(vmin, fminf(fminf(v.x, v.y), fminf(v.z, v.w)));
        vmax = fmaxf(vmax, fmaxf(fmaxf(v.x, v.y), fmaxf(v.z, v.w)));
    }
    __shared__ float smn[4], smx[4];
#pragma unroll
    for (int off = 32; off > 0; off >>= 1){
        vmin = fminf(vmin, __shfl_down(vmin, off));
        vmax = fmaxf(vmax, __shfl_down(vmax, off));
    }
    int wv = threadIdx.x >> 6;
    if ((threadIdx.x & 63) == 0){ smn[wv] = vmin; smx[wv] = vmax; }
    __syncthreads();
    if (threadIdx.x == 0){
        wsf[2*blk]     = fminf(fminf(smn[0], smn[1]), fminf(smn[2], smn[3]));
        wsf[2*blk + 1] = fmaxf(fmaxf(smx[0], smx[1]), fmaxf(smx[2], smx[3]));
    }
}

// grid: 96 blocks, one per (b,cls) record; 64 threads.
__global__ __launch_bounds__(64) void k_prep(const int* __restrict__ index, const float* __restrict__ param,
                       const float* __restrict__ w1, const float* __restrict__ b1,
                       const float* __restrict__ w2, const float* __restrict__ b2,
                       float* __restrict__ wsf){
    __shared__ float w1s[108], w2s[108], b1s[12], b2s[3], prm[21];
    const int r = blockIdx.x, t = threadIdx.x;
    if (r == 0 && t < 16){
        float mn = 1e30f, mx = -1e30f;
        for (int c = 0; c < 16; c++){
            mn = fminf(mn, wsf[2*(t*16 + c)]);
            mx = fmaxf(mx, wsf[2*(t*16 + c) + 1]);
        }
        float sc = mx - mn + 1e-8f;
        wsf[OFF_MN + t] = mn; wsf[OFF_SC + t] = sc; wsf[OFF_INV + t] = 1.0f / sc;
    }
    const int b = r / 6, i = r % 6;
    const int lb0 = (index[b]*CNUM_ + i) * 12;   // (idx, i, aug=0) * LNUM, + l
    for (int k = t; k < 108; k += 64){
        int l = k / 36, j = k % 36;
        w1s[k] = w1[(lb0 + l)*36 + j];
        w2s[k] = w2[(lb0 + l)*36 + j];
    }
    if (t < 12) b1s[t] = b1[(lb0 + t/4)*4 + (t%4)];
    if (t < 3)  b2s[t] = b2[lb0 + t];
    if (t < 21) prm[t] = param[(lb0 + t/7)*7 + (t%7)];
    __syncthreads();
    float* rec = wsf + RECBASE + r*REC_F;
    float* var = wsf + VARBASE + r*9*3*VAR_F;
    for (int u = t; u < 9*3*26; u += 64){
        int kind = u / 78, rem = u % 78, l = rem / 26, e = rem % 26;
        int rowk = kind / 3, colk = kind % 3;
        if (e < 25){
            int ty = e/5 - 2, tx = e%5 - 2;
            float we = 0.f;
            for (int d = 0; d < 9; d++){
                int dy = d/3 - 1, dx = d%3 - 1;
                if ((rowk==0 && dy<0)||(rowk==2 && dy>0)||(colk==0 && dx<0)||(colk==2 && dx>0)) continue;
                int ey = ty - dy, ex = tx - dx;
                if (ey < -1 || ey > 1 || ex < -1 || ex > 1) continue;
                for (int c = 0; c < 4; c++)
                    we += w2s[l*36 + c*9 + d] * w1s[l*36 + c*9 + (ey+1)*3 + (ex+1)];
            }
            var[(kind*3 + l)*VAR_F + e] = we;
            if (kind == 4) rec[l*25 + e] = we;
        } else {
            float be = b2s[l];
            for (int c = 0; c < 4; c++){
                float sw = 0.f;
                for (int d = 0; d < 9; d++){
                    int dy = d/3 - 1, dx = d%3 - 1;
                    if ((rowk==0 && dy<0)||(rowk==2 && dy>0)||(colk==0 && dx<0)||(colk==2 && dx>0)) continue;
                    sw += w2s[l*36 + c*9 + d];
                }
                be += b1s[l*4 + c] * sw;
            }
            var[(kind*3 + l)*VAR_F + 25] = be;
            if (kind == 4) rec[75 + l] = be;
        }
    }
    if (t < 18){   // bezier cubic Horner coeffs: l = t/6, q = t%6
        int l = t / 6, q = t % 6;
        float p1  = 1.f/(1.f + __expf(-prm[l*7 + 0]));
        float p2  = 1.f/(1.f + __expf(-prm[l*7 + 1]));
        float p1v = 1.f/(1.f + __expf(-prm[l*7 + 2]));
        float p2v = 1.f/(1.f + __expf(-prm[l*7 + 3]));
        float v;
        switch (q){
            case 0: v = 3.f*p1; break;
            case 1: v = 3.f*p2 - 6.f*p1; break;
            case 2: v = 1.f + 3.f*p1 - 3.f*p2; break;
            case 3: v = 3.f*p1v - 3.f; break;
            case 4: v = 3.f - 6.f*p1v + 3.f*p2v; break;
            default: v = -1.f + 3.f*p1v - 3.f*p2v; break;
        }
        rec[78 + l*6 + q] = v;
    }
}

__device__ __forceinline__ float bez3(float c, float mix, const float* __restrict__ cf){
    float ct = c * (cf[0] + c * (cf[1] + c * cf[2]));
    float cv = 1.f + c * (cf[3] + c * (cf[4] + c * cf[5]));
    float r = cv + mix * (ct - cv);
    return __builtin_amdgcn_fmed3f(r, 0.f, 1.f);
}

// load 25 taps from two positive-offset bases (read2-friendly immediates)
__device__ __forceinline__ void load_taps(const float* __restrict__ s, int pos, float* tp){
    const float* sp0 = s + pos - (2*SSTR + 2);   // rows 0..2
    const float* sp1 = s + pos + (SSTR - 2);     // rows 3..4
#pragma unroll
    for (int wy = 0; wy < 3; wy++)
#pragma unroll
    for (int wx = 0; wx < 5; wx++)
        tp[wy*5 + wx] = sp0[wy*SSTR + wx];
#pragma unroll
    for (int wy = 0; wy < 2; wy++)
#pragma unroll
    for (int wx = 0; wx < 5; wx++)
        tp[15 + wy*5 + wx] = sp1[wy*SSTR + wx];
}

// packed-f32 conv on preloaded taps + Horner bezier epilogue
__device__ __forceinline__ float proc_tp(const float* tp, const float* __restrict__ rec){
    f2 a0 = {rec[75], 0.f};
    f2 a1 = {rec[76], 0.f};
    f2 a2 = {rec[77], 0.f};
#pragma unroll
    for (int e = 0; e < 24; e += 2){
        f2 tv = {tp[e], tp[e+1]};
        f2 w0 = {rec[e],      rec[e+1]};
        f2 w1 = {rec[25 + e], rec[26 + e]};
        f2 w2 = {rec[50 + e], rec[51 + e]};
        a0 += w0 * tv;
        a1 += w1 * tv;
        a2 += w2 * tv;
    }
    float t24 = tp[24];
    float s0 = a0.x + a0.y + rec[24]*t24;
    float s1 = a1.x + a1.y + rec[49]*t24;
    float s2 = a2.x + a2.y + rec[74]*t24;
    float c = tp[12];
    c = bez3(c, 1.0f/(1.0f + __expf(-s0)), rec + 78);
    c = bez3(c, 1.0f/(1.0f + __expf(-s1)), rec + 84);
    c = bez3(c, 1.0f/(1.0f + __expf(-s2)), rec + 90);
    return c;
}

__global__ __launch_bounds__(NT, 8) void k_main(
        const float* __restrict__ x, const int* __restrict__ lbl,
        float* __restrict__ out, const float* __restrict__ wsf){
    __shared__ float s[ST*SSTR];                 // 12768 B
    __shared__ unsigned short lst[LTOT];         // 5760 B
    __shared__ unsigned rlst[RCAP];              // 512 B
    __shared__ int cnt[8];
    // XCD-aware swizzle: id&7 -> XCD; each XCD owns 512 contiguous tiles = 2 images
    const int lin = ((blockIdx.z << 4) + blockIdx.y) * 16 + blockIdx.x;
    const int tile = ((lin & 7) << 9) + (lin >> 3);
    const int bz = tile >> 8, by = (tile >> 4) & 15, bx = tile & 15;
    const int b = bz;
    const int X0 = bx * TILE - HALO, Y0 = by * TILE - HALO;
    const float mn = wsf[OFF_MN + b], sc = wsf[OFF_SC + b], inv = wsf[OFF_INV + b];
    const float mninv = mn * inv;
    const int tid = threadIdx.x;
    const int lane = tid & 63;
    const int sbase = b * IMG;
    const bool edgeblk = (bx == 0) | (bx == 15) | (by == 0) | (by == 15);

    if (tid < 8) cnt[tid] = 0;
    __syncthreads();

    // ---- stage + classify in one sweep (3-bit ballot classification;
    //      non-listed pixels encoded as class 7 -> no validity ballot) ----
    for (int it = 0; it < 13; it++){
        int k = it*NT + tid;
        bool inb = k < ST*ST;
        int ly = k / ST, lx = k % ST;
        int gy = Y0 + ly, gx = X0 + lx;
        bool valid = inb && (unsigned)gy < (unsigned)HW && (unsigned)gx < (unsigned)HW;
        float v = 0.f; int c = 255;
        if (valid){
            int off = sbase + gy*HW + gx;
            v = x[off]*inv - mninv;
            c = lbl[off];
        }
        if (inb) s[ly*SSTR + lx] = v;
        int margin = min(min(lx, ST-1-lx), min(ly, ST-1-ly));
        bool ring = valid && ((gx==0) | (gx==HW-1) | (gy==0) | (gy==HW-1));
        bool mainok = valid && !ring && c < CNUM_ && margin >= 2 + 2*c;
        int ce = mainok ? c : 7;
        unsigned short pos = (unsigned short)(ly*SSTR + lx);

        unsigned long long m0 = __ballot(ce & 1);
        unsigned long long m1 = __ballot(ce & 2);
        unsigned long long m2 = __ballot(ce & 4);
        int basev = 0;
        if (lane < 6){
            unsigned long long mc = ((lane & 1) ? m0 : ~m0)
                                  & ((lane & 2) ? m1 : ~m1)
                                  & ((lane & 4) ? m2 : ~m2);
            int pc = __popcll(mc);
            if (pc) basev = atomicAdd(&cnt[lane], pc);
        }
        int mybase = __shfl(basev, ce < 6 ? ce : 0);
        if (mainok){
            unsigned long long mself = ((ce & 1) ? m0 : ~m0)
                                     & ((ce & 2) ? m1 : ~m1)
                                     & ((ce & 4) ? m2 : ~m2);
            int p = mybase + __popcll(mself & ((1ull << lane) - 1ull));
            int capc = 640 - (ce << 6);
            int offc = ce * (672 - (ce << 5));
            if (p < capc) lst[offc + p] = pos;
        }
        if (edgeblk){
            bool ringok = ring && c < CNUM_ && margin >= 2;
            unsigned long long rm = __ballot(ringok);
            if (rm){
                int base = 0;
                if (lane == 0) base = atomicAdd(&cnt[6], __popcll(rm));
                base = __shfl(base, 0);
                if (ringok){
                    int p = base + __popcll(rm & ((1ull << lane) - 1ull));
                    if (p < RCAP) rlst[p] = ((unsigned)c << 16) | pos;
                }
            }
        }
    }
    __syncthreads();
    const int rn = min(cnt[6], RCAP);

    // ---- 6 class passes over compacted lists (two-deep tap pipeline) ----
#pragma unroll
    for (int cls = 0; cls < CNUM_; cls++){
        const int capc = 640 - 64*cls;
        const int offc = cls * (672 - 32*cls);
        const float* rec = wsf + RECBASE + (b*CNUM_ + cls)*REC_F;
        const int n = min(cnt[cls], capc);
        const unsigned short* lp = lst + offc;
        const int j0 = tid, j1 = tid + NT, j2 = tid + 2*NT;
        const bool a0 = j0 < n, a1 = j1 < n, a2 = j2 < n;
        int p0 = 0, p1 = 0, p2 = 0;
        if (a0) p0 = lp[j0];
        if (a1) p1 = lp[j1];
        if (a2) p2 = lp[j2];
        float tpA[25], tpB[25];
        float u0, u1, u2;
        if (a0) load_taps(s, p0, tpA);
        if (a1) load_taps(s, p1, tpB);
        if (a0) u0 = proc_tp(tpA, rec);
        if (a2) load_taps(s, p2, tpA);   // reuse A after u0 consumed it
        if (a1) u1 = proc_tp(tpB, rec);
        if (a2) u2 = proc_tp(tpA, rec);
        // ring pixels (image border): exact border-variant composed weights
        int hav = -1; float rupd = 0.f;
        if (edgeblk && tid < rn){
            unsigned e = rlst[tid];
            int rc = (int)(e >> 16), pos = (int)(e & 0xffff);
            int ly = pos / SSTR, lx = pos % SSTR;
            int margin = min(min(lx, ST-1-lx), min(ly, ST-1-ly));
            if (rc == cls && margin >= 2 + 2*cls){
                int gy = Y0 + ly, gx = X0 + lx;
                int rowk = (gy == 0) ? 0 : ((gy == HW-1) ? 2 : 1);
                int colk = (gx == 0) ? 0 : ((gx == HW-1) ? 2 : 1);
                const float* vb = wsf + VARBASE + ((b*CNUM_ + cls)*9 + rowk*3 + colk)*3*VAR_F;
                float tp[25];
                load_taps(s, pos, tp);
                float c = tp[12];
#pragma unroll
                for (int l = 0; l < 3; l++){
                    float z = vb[l*VAR_F + 25];
#pragma unroll
                    for (int e2 = 0; e2 < 25; e2++) z += vb[l*VAR_F + e2] * tp[e2];
                    c = bez3(c, 1.0f/(1.0f + __expf(-z)), rec + 78 + 6*l);
                }
                rupd = c; hav = pos;
            }
        }
        __syncthreads();   // all pass-start reads complete
        if (a0) s[p0] = u0;
        if (a1) s[p1] = u1;
        if (a2) s[p2] = u2;
        if (hav >= 0) s[hav] = rupd;
        __syncthreads();   // writes visible before next pass
    }

    // ---- denormalized core store ----
    for (int j = tid; j < TILE*TILE; j += NT){
        int py = j >> 5, px = j & 31;
        int gy = Y0 + HALO + py, gx = X0 + HALO + px;
        out[sbase + gy*HW + gx] = s[(HALO + py)*SSTR + (HALO + px)] * sc + mn;
    }
}

extern "C" void kernel_launch(void* const* d_in, const int* in_sizes, int n_in,
                              void* d_out, int out_size, void* d_ws, size_t ws_size,
                              hipStream_t stream){
    const float* x     = (const float*)d_in[0];
    const int*   lbl   = (const int*)  d_in[1];
    const int*   index = (const int*)  d_in[2];
    const float* param = (const float*)d_in[3];
    const float* w1    = (const float*)d_in[4];
    const float* b1    = (const float*)d_in[5];
    const float* w2    = (const float*)d_in[6];
    const float* b2    = (const float*)d_in[7];
    float* out = (float*)d_out;
    float* wsf = (float*)d_ws;

    k_minmax<<<256, 256, 0, stream>>>((const float4*)x, wsf);
    k_prep<<<96, 64, 0, stream>>>(index, param, w1, b1, w2, b2, wsf);
    dim3 g(16, 16, 16);
    k_main<<<g, NT, 0, stream>>>(x, lbl, out, wsf);
}

// Round 11
// 209.741 us; speedup vs baseline: 1.2630x; 1.2630x over previous
//
#include <hip/hip_runtime.h>
#include <stdint.h>

#define HW 512
#define IMG (HW*HW)
#define CNUM_ 6

#define TILE 32
#define HALO 12
#define ST 56            // staged tile edge
#define SSTR 60          // LDS row stride (floats), mult of 4 for b128 staging
#define NT 256
#define RCAP 128         // ring list cap (structural max ~104)
#define DUMMY (2*SSTR+2) // safe dummy pos for pair padding (reads in-bounds, write masked)

typedef float f2 __attribute__((ext_vector_type(2)));

// per-class list caps/offsets: cap(c) = 640-64c, off(c) = c*(672-32c)
#define LTOT 2880

// ws float layout:
// [0..511]   per-block minmax partials (min at 2k, max at 2k+1)
// [512..527] mn  [528..543] sc  [544..559] inv
// [RECBASE + r*REC_F]  r=(b*6+cls):
//   [0..74] weff (l*25+e), [75..77] beff, [78..95] bezier Horner coeffs (l*6+q)
// [VARBASE + (r*9+kind)*3*VAR_F + l*VAR_F]: border-variant [0..24] w, [25] bias
#define OFF_MN 512
#define OFF_SC 528
#define OFF_INV 544
#define RECBASE 1024
#define REC_F 96
#define VARBASE (RECBASE + 96*REC_F)
#define VAR_F 27

__global__ __launch_bounds__(256) void k_minmax(const float4* __restrict__ x, float* __restrict__ wsf){
    int blk = blockIdx.x;            // blk = b*16 + chunk
    int base4 = blk * 4096;
    float vmin = 1e30f, vmax = -1e30f;
#pragma unroll
    for (int k = 0; k < 16; k++){
        float4 v = x[base4 + k*256 + threadIdx.x];
        vmin = fminf(vmin, fminf(fminf(v.x, v.y), fminf(v.z, v.w)));
        vmax = fmaxf(vmax, fmaxf(fmaxf(v.x, v.y), fmaxf(v.z, v.w)));
    }
    __shared__ float smn[4], smx[4];
#pragma unroll
    for (int off = 32; off > 0; off >>= 1){
        vmin = fminf(vmin, __shfl_down(vmin, off));
        vmax = fmaxf(vmax, __shfl_down(vmax, off));
    }
    int wv = threadIdx.x >> 6;
    if ((threadIdx.x & 63) == 0){ smn[wv] = vmin; smx[wv] = vmax; }
    __syncthreads();
    if (threadIdx.x == 0){
        wsf[2*blk]     = fminf(fminf(smn[0], smn[1]), fminf(smn[2], smn[3]));
        wsf[2*blk + 1] = fmaxf(fmaxf(smx[0], smx[1]), fmaxf(smx[2], smx[3]));
    }
}

// grid: 96 blocks, one per (b,cls) record; 64 threads.
__global__ __launch_bounds__(64) void k_prep(const int* __restrict__ index, const float* __restrict__ param,
                       const float* __restrict__ w1, const float* __restrict__ b1,
                       const float* __restrict__ w2, const float* __restrict__ b2,
                       float* __restrict__ wsf){
    __shared__ float w1s[108], w2s[108], b1s[12], b2s[3], prm[21];
    const int r = blockIdx.x, t = threadIdx.x;
    if (r == 0 && t < 16){
        float mn = 1e30f, mx = -1e30f;
        for (int c = 0; c < 16; c++){
            mn = fminf(mn, wsf[2*(t*16 + c)]);
            mx = fmaxf(mx, wsf[2*(t*16 + c) + 1]);
        }
        float sc = mx - mn + 1e-8f;
        wsf[OFF_MN + t] = mn; wsf[OFF_SC + t] = sc; wsf[OFF_INV + t] = 1.0f / sc;
    }
    const int b = r / 6, i = r % 6;
    const int lb0 = (index[b]*CNUM_ + i) * 12;   // (idx, i, aug=0) * LNUM, + l
    for (int k = t; k < 108; k += 64){
        int l = k / 36, j = k % 36;
        w1s[k] = w1[(lb0 + l)*36 + j];
        w2s[k] = w2[(lb0 + l)*36 + j];
    }
    if (t < 12) b1s[t] = b1[(lb0 + t/4)*4 + (t%4)];
    if (t < 3)  b2s[t] = b2[lb0 + t];
    if (t < 21) prm[t] = param[(lb0 + t/7)*7 + (t%7)];
    __syncthreads();
    float* rec = wsf + RECBASE + r*REC_F;
    float* var = wsf + VARBASE + r*9*3*VAR_F;
    for (int u = t; u < 9*3*26; u += 64){
        int kind = u / 78, rem = u % 78, l = rem / 26, e = rem % 26;
        int rowk = kind / 3, colk = kind % 3;
        if (e < 25){
            int ty = e/5 - 2, tx = e%5 - 2;
            float we = 0.f;
            for (int d = 0; d < 9; d++){
                int dy = d/3 - 1, dx = d%3 - 1;
                if ((rowk==0 && dy<0)||(rowk==2 && dy>0)||(colk==0 && dx<0)||(colk==2 && dx>0)) continue;
                int ey = ty - dy, ex = tx - dx;
                if (ey < -1 || ey > 1 || ex < -1 || ex > 1) continue;
                for (int c = 0; c < 4; c++)
                    we += w2s[l*36 + c*9 + d] * w1s[l*36 + c*9 + (ey+1)*3 + (ex+1)];
            }
            var[(kind*3 + l)*VAR_F + e] = we;
            if (kind == 4) rec[l*25 + e] = we;
        } else {
            float be = b2s[l];
            for (int c = 0; c < 4; c++){
                float sw = 0.f;
                for (int d = 0; d < 9; d++){
                    int dy = d/3 - 1, dx = d%3 - 1;
                    if ((rowk==0 && dy<0)||(rowk==2 && dy>0)||(colk==0 && dx<0)||(colk==2 && dx>0)) continue;
                    sw += w2s[l*36 + c*9 + d];
                }
                be += b1s[l*4 + c] * sw;
            }
            var[(kind*3 + l)*VAR_F + 25] = be;
            if (kind == 4) rec[75 + l] = be;
        }
    }
    if (t < 18){   // bezier cubic Horner coeffs: l = t/6, q = t%6
        int l = t / 6, q = t % 6;
        float p1  = 1.f/(1.f + __expf(-prm[l*7 + 0]));
        float p2  = 1.f/(1.f + __expf(-prm[l*7 + 1]));
        float p1v = 1.f/(1.f + __expf(-prm[l*7 + 2]));
        float p2v = 1.f/(1.f + __expf(-prm[l*7 + 3]));
        float v;
        switch (q){
            case 0: v = 3.f*p1; break;
            case 1: v = 3.f*p2 - 6.f*p1; break;
            case 2: v = 1.f + 3.f*p1 - 3.f*p2; break;
            case 3: v = 3.f*p1v - 3.f; break;
            case 4: v = 3.f - 6.f*p1v + 3.f*p2v; break;
            default: v = -1.f + 3.f*p1v - 3.f*p2v; break;
        }
        rec[78 + l*6 + q] = v;
    }
}

__device__ __forceinline__ float bez3(float c, float mix, const float* __restrict__ cf){
    float ct = c * (cf[0] + c * (cf[1] + c * cf[2]));
    float cv = 1.f + c * (cf[3] + c * (cf[4] + c * cf[5]));
    float r = cv + mix * (ct - cv);
    return __builtin_amdgcn_fmed3f(r, 0.f, 1.f);
}

// packed bezier across pixel pair
__device__ __forceinline__ f2 bez3p(f2 c, f2 mix, const float* __restrict__ cf){
    f2 k0 = {cf[0], cf[0]}, k1 = {cf[1], cf[1]}, k2 = {cf[2], cf[2]};
    f2 k3 = {cf[3], cf[3]}, k4 = {cf[4], cf[4]}, k5 = {cf[5], cf[5]};
    f2 ct = c * (k0 + c * (k1 + c * k2));
    f2 cv = f2{1.f, 1.f} + c * (k3 + c * (k4 + c * k5));
    f2 r = cv + mix * (ct - cv);
    r.x = __builtin_amdgcn_fmed3f(r.x, 0.f, 1.f);
    r.y = __builtin_amdgcn_fmed3f(r.y, 0.f, 1.f);
    return r;
}

// two-pixel packed transform: f2 components = (pxA, pxB); taps consumed
// immediately (no private arrays -> no scratch); weights wave-uniform.
__device__ __forceinline__ f2 proc_pair(const float* __restrict__ s, int posA, int posB,
                                        const float* __restrict__ rec){
    const float* A0 = s + posA - (2*SSTR + 2);
    const float* A1 = s + posA + (SSTR - 2);
    const float* B0 = s + posB - (2*SSTR + 2);
    const float* B1 = s + posB + (SSTR - 2);
    f2 a0 = {rec[75], rec[75]};
    f2 a1 = {rec[76], rec[76]};
    f2 a2 = {rec[77], rec[77]};
    f2 ctr = {0.f, 0.f};
#pragma unroll
    for (int e = 0; e < 25; e++){
        const int wy = e / 5, wx = e % 5;
        float tA = (wy < 3) ? A0[wy*SSTR + wx] : A1[(wy-3)*SSTR + wx];
        float tB = (wy < 3) ? B0[wy*SSTR + wx] : B1[(wy-3)*SSTR + wx];
        f2 tv = {tA, tB};
        if (e == 12) ctr = tv;
        a0 += f2{rec[e],      rec[e]}      * tv;
        a1 += f2{rec[25 + e], rec[25 + e]} * tv;
        a2 += f2{rec[50 + e], rec[50 + e]} * tv;
    }
    f2 c = ctr, m;
    m.x = 1.0f/(1.0f + __expf(-a0.x)); m.y = 1.0f/(1.0f + __expf(-a0.y));
    c = bez3p(c, m, rec + 78);
    m.x = 1.0f/(1.0f + __expf(-a1.x)); m.y = 1.0f/(1.0f + __expf(-a1.y));
    c = bez3p(c, m, rec + 84);
    m.x = 1.0f/(1.0f + __expf(-a2.x)); m.y = 1.0f/(1.0f + __expf(-a2.y));
    c = bez3p(c, m, rec + 90);
    return c;
}

// scalar tap loader for the (rare) ring path
__device__ __forceinline__ void load_taps(const float* __restrict__ s, int pos, float* tp){
    const float* sp0 = s + pos - (2*SSTR + 2);
    const float* sp1 = s + pos + (SSTR - 2);
#pragma unroll
    for (int wy = 0; wy < 3; wy++)
#pragma unroll
    for (int wx = 0; wx < 5; wx++)
        tp[wy*5 + wx] = sp0[wy*SSTR + wx];
#pragma unroll
    for (int wy = 0; wy < 2; wy++)
#pragma unroll
    for (int wx = 0; wx < 5; wx++)
        tp[15 + wy*5 + wx] = sp1[wy*SSTR + wx];
}

__global__ __launch_bounds__(NT, 8) void k_main(
        const float* __restrict__ x, const int* __restrict__ lbl,
        float* __restrict__ out, const float* __restrict__ wsf){
    __shared__ __align__(16) float s[ST*SSTR];   // 13440 B
    __shared__ unsigned short lst[LTOT];         // 5760 B
    __shared__ unsigned rlst[RCAP];              // 512 B
    __shared__ int cnt[8];
    // XCD-aware swizzle: id&7 -> XCD; each XCD owns 512 contiguous tiles = 2 images
    const int lin = ((blockIdx.z << 4) + blockIdx.y) * 16 + blockIdx.x;
    const int tile = ((lin & 7) << 9) + (lin >> 3);
    const int bz = tile >> 8, by = (tile >> 4) & 15, bx = tile & 15;
    const int b = bz;
    const int X0 = bx * TILE - HALO, Y0 = by * TILE - HALO;
    const float mn = wsf[OFF_MN + b], sc = wsf[OFF_SC + b], inv = wsf[OFF_INV + b];
    const float mninv = mn * inv;
    const int tid = threadIdx.x;
    const int lane = tid & 63;
    const int sbase = b * IMG;
    const bool edgeblk = (bx == 0) | (bx == 15) | (by == 0) | (by == 15);

    if (tid < 8) cnt[tid] = 0;
    __syncthreads();

    // ---- stage (float4/int4 groups; X0 % 4 == 0 so groups are all-in/all-out)
    //      + classify (3-bit ballots; non-listed pixels encoded class 7) ----
    for (int it = 0; it < 4; it++){
        int k4 = it*NT + tid;                 // group id, 0..783
        bool inb = k4 < 14*ST;
        int row = k4 / 14, lx0 = (k4 % 14) * 4;
        int gy = Y0 + row, gxs = X0 + lx0;
        bool gvalid = inb && (unsigned)gy < (unsigned)HW && (unsigned)gxs < (unsigned)HW;
        float4 v = {0.f, 0.f, 0.f, 0.f};
        int4 lb = {255, 255, 255, 255};
        if (gvalid){
            int off = sbase + gy*HW + gxs;
            v  = *(const float4*)(x + off);
            lb = *(const int4*)(lbl + off);
            v.x = v.x*inv - mninv; v.y = v.y*inv - mninv;
            v.z = v.z*inv - mninv; v.w = v.w*inv - mninv;
        }
        if (inb) *(float4*)(s + row*SSTR + lx0) = v;
        int my = min(row, ST-1-row);
#pragma unroll
        for (int i = 0; i < 4; i++){
            int lxx = lx0 + i, gx = gxs + i;
            int c = (i==0) ? lb.x : (i==1) ? lb.y : (i==2) ? lb.z : lb.w;
            int margin = min(min(lxx, ST-1-lxx), my);
            bool ring = gvalid && ((gx==0) | (gx==HW-1) | (gy==0) | (gy==HW-1));
            bool mainok = gvalid && !ring && c < CNUM_ && margin >= 2 + 2*c;
            int ce = mainok ? c : 7;
            unsigned short pos = (unsigned short)(row*SSTR + lxx);

            unsigned long long m0 = __ballot(ce & 1);
            unsigned long long m1 = __ballot(ce & 2);
            unsigned long long m2 = __ballot(ce & 4);
            int basev = 0;
            if (lane < 6){
                unsigned long long mc = ((lane & 1) ? m0 : ~m0)
                                      & ((lane & 2) ? m1 : ~m1)
                                      & ((lane & 4) ? m2 : ~m2);
                int pc = __popcll(mc);
                if (pc) basev = atomicAdd(&cnt[lane], pc);
            }
            int mybase = __shfl(basev, ce < 6 ? ce : 0);
            if (mainok){
                unsigned long long mself = ((ce & 1) ? m0 : ~m0)
                                         & ((ce & 2) ? m1 : ~m1)
                                         & ((ce & 4) ? m2 : ~m2);
                int p = mybase + __popcll(mself & ((1ull << lane) - 1ull));
                int capc = 640 - (ce << 6);
                int offc = ce * (672 - (ce << 5));
                if (p < capc) lst[offc + p] = pos;
            }
            if (edgeblk){
                bool ringok = ring && c < CNUM_ && margin >= 2;
                unsigned long long rm = __ballot(ringok);
                if (rm){
                    int base = 0;
                    if (lane == 0) base = atomicAdd(&cnt[6], __popcll(rm));
                    base = __shfl(base, 0);
                    if (ringok){
                        int p = base + __popcll(rm & ((1ull << lane) - 1ull));
                        if (p < RCAP) rlst[p] = ((unsigned)c << 16) | pos;
                    }
                }
            }
        }
    }
    __syncthreads();
    const int rn = min(cnt[6], RCAP);

    // ---- 6 class passes: paired packed compute over compacted lists ----
#pragma unroll
    for (int cls = 0; cls < CNUM_; cls++){
        const int capc = 640 - 64*cls;
        const int offc = cls * (672 - 32*cls);
        const float* rec = wsf + RECBASE + (b*CNUM_ + cls)*REC_F;
        const int n = min(cnt[cls], capc);
        const unsigned short* lp = lst + offc;
        const int jA = 2*tid, jB = jA + 1;
        const bool run = jA < n;
        int pA = DUMMY, pB = DUMMY;
        f2 u = {0.f, 0.f};
        if (run){
            pA = lp[jA];
            if (jB < n) pB = lp[jB];
            u = proc_pair(s, pA, pB, rec);
        }
        int pS = DUMMY; float uS = 0.f; bool runS = false;
        if (capc > 512){                       // singles tail (cls 0,1 only)
            int jS = 512 + tid;
            runS = jS < n;
            if (runS){
                pS = lp[jS];
                f2 t = proc_pair(s, pS, DUMMY, rec);
                uS = t.x;
            }
        }
        // ring pixels (image border): exact border-variant composed weights
        int hav = -1; float rupd = 0.f;
        if (edgeblk && tid < rn){
            unsigned e = rlst[tid];
            int rc = (int)(e >> 16), pos = (int)(e & 0xffff);
            int ly = pos / SSTR, lx = pos % SSTR;
            int margin = min(min(lx, ST-1-lx), min(ly, ST-1-ly));
            if (rc == cls && margin >= 2 + 2*cls){
                int gy = Y0 + ly, gx = X0 + lx;
                int rowk = (gy == 0) ? 0 : ((gy == HW-1) ? 2 : 1);
                int colk = (gx == 0) ? 0 : ((gx == HW-1) ? 2 : 1);
                const float* vb = wsf + VARBASE + ((b*CNUM_ + cls)*9 + rowk*3 + colk)*3*VAR_F;
                float tp[25];
                load_taps(s, pos, tp);
                float c = tp[12];
#pragma unroll
                for (int l = 0; l < 3; l++){
                    float z = vb[l*VAR_F + 25];
#pragma unroll
                    for (int e2 = 0; e2 < 25; e2++) z += vb[l*VAR_F + e2] * tp[e2];
                    c = bez3(c, 1.0f/(1.0f + __expf(-z)), rec + 78 + 6*l);
                }
                rupd = c; hav = pos;
            }
        }
        __syncthreads();   // all pass-start reads complete
        if (run){
            s[pA] = u.x;
            if (jB < n) s[pB] = u.y;
        }
        if (runS) s[pS] = uS;
        if (hav >= 0) s[hav] = rupd;
        __syncthreads();   // writes visible before next pass
    }

    // ---- denormalized core store ----
    for (int j = tid; j < TILE*TILE; j += NT){
        int py = j >> 5, px = j & 31;
        int gy = Y0 + HALO + py, gx = X0 + HALO + px;
        out[sbase + gy*HW + gx] = s[(HALO + py)*SSTR + (HALO + px)] * sc + mn;
    }
}

extern "C" void kernel_launch(void* const* d_in, const int* in_sizes, int n_in,
                              void* d_out, int out_size, void* d_ws, size_t ws_size,
                              hipStream_t stream){
    const float* x     = (const float*)d_in[0];
    const int*   lbl   = (const int*)  d_in[1];
    const int*   index = (const int*)  d_in[2];
    const float* param = (const float*)d_in[3];
    const float* w1    = (const float*)d_in[4];
    const float* b1    = (const float*)d_in[5];
    const float* w2    = (const float*)d_in[6];
    const float* b2    = (const float*)d_in[7];
    float* out = (float*)d_out;
    float* wsf = (float*)d_ws;

    k_minmax<<<256, 256, 0, stream>>>((const float4*)x, wsf);
    k_prep<<<96, 64, 0, stream>>>(index, param, w1, b1, w2, b2, wsf);
    dim3 g(16, 16, 16);
    k_main<<<g, NT, 0, stream>>>(x, lbl, out, wsf);
}

// Round 12
// 191.420 us; speedup vs baseline: 1.3838x; 1.0957x over previous
//
#include <hip/hip_runtime.h>
#include <stdint.h>

#define HW 512
#define IMG (HW*HW)
#define CNUM_ 6

#define TILE 32
#define HALO 12
#define ST 56            // staged tile edge
#define SSTR 57          // LDS row stride (floats)
#define NT 256
#define RCAP 128         // ring list cap (structural max ~104)

typedef float f2 __attribute__((ext_vector_type(2)));

// per-class list caps/offsets: cap(c) = 640-64c, off(c) = c*(672-32c)
#define LTOT 2880

// ws float layout:
// [0..511]   per-block minmax partials (min at 2k, max at 2k+1)
// [512..527] mn  [528..543] sc  [544..559] inv
// [RECBASE + r*REC_F]  r=(b*6+cls):
//   [0..74] weff (l*25+e), [75..77] beff, [78..95] bezier Horner coeffs (l*6+q)
// [VARBASE + (r*9+kind)*3*VAR_F + l*VAR_F]: border-variant [0..24] w, [25] bias
#define OFF_MN 512
#define OFF_SC 528
#define OFF_INV 544
#define RECBASE 1024
#define REC_F 96
#define VARBASE (RECBASE + 96*REC_F)
#define VAR_F 27

__global__ __launch_bounds__(256) void k_minmax(const float4* __restrict__ x, float* __restrict__ wsf){
    int blk = blockIdx.x;            // blk = b*16 + chunk
    int base4 = blk * 4096;
    float vmin = 1e30f, vmax = -1e30f;
#pragma unroll
    for (int k = 0; k < 16; k++){
        float4 v = x[base4 + k*256 + threadIdx.x];
        vmin = fminf(vmin, fminf(fminf(v.x, v.y), fminf(v.z, v.w)));
        vmax = fmaxf(vmax, fmaxf(fmaxf(v.x, v.y), fmaxf(v.z, v.w)));
    }
    __shared__ float smn[4], smx[4];
#pragma unroll
    for (int off = 32; off > 0; off >>= 1){
        vmin = fminf(vmin, __shfl_down(vmin, off));
        vmax = fmaxf(vmax, __shfl_down(vmax, off));
    }
    int wv = threadIdx.x >> 6;
    if ((threadIdx.x & 63) == 0){ smn[wv] = vmin; smx[wv] = vmax; }
    __syncthreads();
    if (threadIdx.x == 0){
        wsf[2*blk]     = fminf(fminf(smn[0], smn[1]), fminf(smn[2], smn[3]));
        wsf[2*blk + 1] = fmaxf(fmaxf(smx[0], smx[1]), fmaxf(smx[2], smx[3]));
    }
}

// grid: 96 blocks, one per (b,cls) record; 64 threads.
__global__ __launch_bounds__(64) void k_prep(const int* __restrict__ index, const float* __restrict__ param,
                       const float* __restrict__ w1, const float* __restrict__ b1,
                       const float* __restrict__ w2, const float* __restrict__ b2,
                       float* __restrict__ wsf){
    __shared__ float w1s[108], w2s[108], b1s[12], b2s[3], prm[21];
    const int r = blockIdx.x, t = threadIdx.x;
    if (r == 0 && t < 16){
        float mn = 1e30f, mx = -1e30f;
        for (int c = 0; c < 16; c++){
            mn = fminf(mn, wsf[2*(t*16 + c)]);
            mx = fmaxf(mx, wsf[2*(t*16 + c) + 1]);
        }
        float sc = mx - mn + 1e-8f;
        wsf[OFF_MN + t] = mn; wsf[OFF_SC + t] = sc; wsf[OFF_INV + t] = 1.0f / sc;
    }
    const int b = r / 6, i = r % 6;
    const int lb0 = (index[b]*CNUM_ + i) * 12;   // (idx, i, aug=0) * LNUM, + l
    for (int k = t; k < 108; k += 64){
        int l = k / 36, j = k % 36;
        w1s[k] = w1[(lb0 + l)*36 + j];
        w2s[k] = w2[(lb0 + l)*36 + j];
    }
    if (t < 12) b1s[t] = b1[(lb0 + t/4)*4 + (t%4)];
    if (t < 3)  b2s[t] = b2[lb0 + t];
    if (t < 21) prm[t] = param[(lb0 + t/7)*7 + (t%7)];
    __syncthreads();
    float* rec = wsf + RECBASE + r*REC_F;
    float* var = wsf + VARBASE + r*9*3*VAR_F;
    for (int u = t; u < 9*3*26; u += 64){
        int kind = u / 78, rem = u % 78, l = rem / 26, e = rem % 26;
        int rowk = kind / 3, colk = kind % 3;
        if (e < 25){
            int ty = e/5 - 2, tx = e%5 - 2;
            float we = 0.f;
            for (int d = 0; d < 9; d++){
                int dy = d/3 - 1, dx = d%3 - 1;
                if ((rowk==0 && dy<0)||(rowk==2 && dy>0)||(colk==0 && dx<0)||(colk==2 && dx>0)) continue;
                int ey = ty - dy, ex = tx - dx;
                if (ey < -1 || ey > 1 || ex < -1 || ex > 1) continue;
                for (int c = 0; c < 4; c++)
                    we += w2s[l*36 + c*9 + d] * w1s[l*36 + c*9 + (ey+1)*3 + (ex+1)];
            }
            var[(kind*3 + l)*VAR_F + e] = we;
            if (kind == 4) rec[l*25 + e] = we;
        } else {
            float be = b2s[l];
            for (int c = 0; c < 4; c++){
                float sw = 0.f;
                for (int d = 0; d < 9; d++){
                    int dy = d/3 - 1, dx = d%3 - 1;
                    if ((rowk==0 && dy<0)||(rowk==2 && dy>0)||(colk==0 && dx<0)||(colk==2 && dx>0)) continue;
                    sw += w2s[l*36 + c*9 + d];
                }
                be += b1s[l*4 + c] * sw;
            }
            var[(kind*3 + l)*VAR_F + 25] = be;
            if (kind == 4) rec[75 + l] = be;
        }
    }
    if (t < 18){   // bezier cubic Horner coeffs: l = t/6, q = t%6
        int l = t / 6, q = t % 6;
        float p1  = 1.f/(1.f + __expf(-prm[l*7 + 0]));
        float p2  = 1.f/(1.f + __expf(-prm[l*7 + 1]));
        float p1v = 1.f/(1.f + __expf(-prm[l*7 + 2]));
        float p2v = 1.f/(1.f + __expf(-prm[l*7 + 3]));
        float v;
        switch (q){
            case 0: v = 3.f*p1; break;
            case 1: v = 3.f*p2 - 6.f*p1; break;
            case 2: v = 1.f + 3.f*p1 - 3.f*p2; break;
            case 3: v = 3.f*p1v - 3.f; break;
            case 4: v = 3.f - 6.f*p1v + 3.f*p2v; break;
            default: v = -1.f + 3.f*p1v - 3.f*p2v; break;
        }
        rec[78 + l*6 + q] = v;
    }
}

__device__ __forceinline__ float bez3(float c, float mix, const float* __restrict__ cf){
    float ct = c * (cf[0] + c * (cf[1] + c * cf[2]));
    float cv = 1.f + c * (cf[3] + c * (cf[4] + c * cf[5]));
    float r = cv + mix * (ct - cv);
    return __builtin_amdgcn_fmed3f(r, 0.f, 1.f);
}

// load 25 taps from two positive-offset bases (read2-friendly immediates)
__device__ __forceinline__ void load_taps(const float* __restrict__ s, int pos, float* tp){
    const float* sp0 = s + pos - (2*SSTR + 2);   // rows 0..2
    const float* sp1 = s + pos + (SSTR - 2);     // rows 3..4
#pragma unroll
    for (int wy = 0; wy < 3; wy++)
#pragma unroll
    for (int wx = 0; wx < 5; wx++)
        tp[wy*5 + wx] = sp0[wy*SSTR + wx];
#pragma unroll
    for (int wy = 0; wy < 2; wy++)
#pragma unroll
    for (int wx = 0; wx < 5; wx++)
        tp[15 + wy*5 + wx] = sp1[wy*SSTR + wx];
}

// packed-f32 conv with wave-uniform scalar weights + Horner bezier epilogue
__device__ __forceinline__ float proc_px(const float* __restrict__ s, int pos,
                                         const float* __restrict__ rec){
    float tp[25];
    load_taps(s, pos, tp);
    f2 a0 = {rec[75], 0.f};
    f2 a1 = {rec[76], 0.f};
    f2 a2 = {rec[77], 0.f};
#pragma unroll
    for (int e = 0; e < 24; e += 2){
        f2 tv = {tp[e], tp[e+1]};
        f2 w0 = {rec[e],      rec[e+1]};
        f2 w1 = {rec[25 + e], rec[26 + e]};
        f2 w2 = {rec[50 + e], rec[51 + e]};
        a0 += w0 * tv;
        a1 += w1 * tv;
        a2 += w2 * tv;
    }
    float t24 = tp[24];
    float s0 = a0.x + a0.y + rec[24]*t24;
    float s1 = a1.x + a1.y + rec[49]*t24;
    float s2 = a2.x + a2.y + rec[74]*t24;
    float c = tp[12];
    c = bez3(c, 1.0f/(1.0f + __expf(-s0)), rec + 78);
    c = bez3(c, 1.0f/(1.0f + __expf(-s1)), rec + 84);
    c = bez3(c, 1.0f/(1.0f + __expf(-s2)), rec + 90);
    return c;
}

__global__ __launch_bounds__(NT, 8) void k_main(
        const float* __restrict__ x, const int* __restrict__ lbl,
        float* __restrict__ out, const float* __restrict__ wsf){
    __shared__ float s[ST*SSTR];                 // 12768 B
    __shared__ unsigned short lst[LTOT];         // 5760 B
    __shared__ unsigned rlst[RCAP];              // 512 B
    __shared__ int cnt[8];
    // XCD-aware swizzle: id&7 -> XCD; each XCD owns 512 contiguous tiles = 2 images
    const int lin = ((blockIdx.z << 4) + blockIdx.y) * 16 + blockIdx.x;
    const int tile = ((lin & 7) << 9) + (lin >> 3);
    const int bz = tile >> 8, by = (tile >> 4) & 15, bx = tile & 15;
    const int b = bz;
    const int X0 = bx * TILE - HALO, Y0 = by * TILE - HALO;
    const float mn = wsf[OFF_MN + b], sc = wsf[OFF_SC + b], inv = wsf[OFF_INV + b];
    const float mninv = mn * inv;
    const int tid = threadIdx.x;
    const int lane = tid & 63;
    const int sbase = b * IMG;
    const bool edgeblk = (bx == 0) | (bx == 15) | (by == 0) | (by == 15);

    if (tid < 8) cnt[tid] = 0;
    __syncthreads();

    // ---- stage + classify in one sweep (3-bit ballot classification;
    //      non-listed pixels encoded as class 7 -> no validity ballot) ----
    for (int it = 0; it < 13; it++){
        int k = it*NT + tid;
        bool inb = k < ST*ST;
        int ly = k / ST, lx = k % ST;
        int gy = Y0 + ly, gx = X0 + lx;
        bool valid = inb && (unsigned)gy < (unsigned)HW && (unsigned)gx < (unsigned)HW;
        float v = 0.f; int c = 255;
        if (valid){
            int off = sbase + gy*HW + gx;
            v = x[off]*inv - mninv;
            c = lbl[off];
        }
        if (inb) s[ly*SSTR + lx] = v;
        int margin = min(min(lx, ST-1-lx), min(ly, ST-1-ly));
        bool ring = valid && ((gx==0) | (gx==HW-1) | (gy==0) | (gy==HW-1));
        bool mainok = valid && !ring && c < CNUM_ && margin >= 2 + 2*c;
        int ce = mainok ? c : 7;
        unsigned short pos = (unsigned short)(ly*SSTR + lx);

        unsigned long long m0 = __ballot(ce & 1);
        unsigned long long m1 = __ballot(ce & 2);
        unsigned long long m2 = __ballot(ce & 4);
        int basev = 0;
        if (lane < 6){
            unsigned long long mc = ((lane & 1) ? m0 : ~m0)
                                  & ((lane & 2) ? m1 : ~m1)
                                  & ((lane & 4) ? m2 : ~m2);
            int pc = __popcll(mc);
            if (pc) basev = atomicAdd(&cnt[lane], pc);
        }
        int mybase = __shfl(basev, ce < 6 ? ce : 0);
        if (mainok){
            unsigned long long mself = ((ce & 1) ? m0 : ~m0)
                                     & ((ce & 2) ? m1 : ~m1)
                                     & ((ce & 4) ? m2 : ~m2);
            int p = mybase + __popcll(mself & ((1ull << lane) - 1ull));
            int capc = 640 - (ce << 6);
            int offc = ce * (672 - (ce << 5));
            if (p < capc) lst[offc + p] = pos;
        }
        if (edgeblk){
            bool ringok = ring && c < CNUM_ && margin >= 2;
            unsigned long long rm = __ballot(ringok);
            if (rm){
                int base = 0;
                if (lane == 0) base = atomicAdd(&cnt[6], __popcll(rm));
                base = __shfl(base, 0);
                if (ringok){
                    int p = base + __popcll(rm & ((1ull << lane) - 1ull));
                    if (p < RCAP) rlst[p] = ((unsigned)c << 16) | pos;
                }
            }
        }
    }
    __syncthreads();
    const int rn = min(cnt[6], RCAP);

    // ---- 6 class passes over compacted lists ----
#pragma unroll
    for (int cls = 0; cls < CNUM_; cls++){
        const int capc = 640 - 64*cls;
        const int offc = cls * (672 - 32*cls);
        const float* rec = wsf + RECBASE + (b*CNUM_ + cls)*REC_F;
        const int n = min(cnt[cls], capc);
        const unsigned short* lp = lst + offc;
        const int j0 = tid, j1 = tid + NT, j2 = tid + 2*NT;
        int p0 = 0, p1 = 0, p2 = 0;
        float u0, u1, u2;
        if (j0 < n){ p0 = lp[j0]; u0 = proc_px(s, p0, rec); }
        if (j1 < n){ p1 = lp[j1]; u1 = proc_px(s, p1, rec); }
        if (j2 < n){ p2 = lp[j2]; u2 = proc_px(s, p2, rec); }
        // ring pixels (image border): exact border-variant composed weights
        int hav = -1; float rupd = 0.f;
        if (edgeblk && tid < rn){
            unsigned e = rlst[tid];
            int rc = (int)(e >> 16), pos = (int)(e & 0xffff);
            int ly = pos / SSTR, lx = pos % SSTR;
            int margin = min(min(lx, ST-1-lx), min(ly, ST-1-ly));
            if (rc == cls && margin >= 2 + 2*cls){
                int gy = Y0 + ly, gx = X0 + lx;
                int rowk = (gy == 0) ? 0 : ((gy == HW-1) ? 2 : 1);
                int colk = (gx == 0) ? 0 : ((gx == HW-1) ? 2 : 1);
                const float* vb = wsf + VARBASE + ((b*CNUM_ + cls)*9 + rowk*3 + colk)*3*VAR_F;
                float tp[25];
                load_taps(s, pos, tp);
                float c = tp[12];
#pragma unroll
                for (int l = 0; l < 3; l++){
                    float z = vb[l*VAR_F + 25];
#pragma unroll
                    for (int e2 = 0; e2 < 25; e2++) z += vb[l*VAR_F + e2] * tp[e2];
                    c = bez3(c, 1.0f/(1.0f + __expf(-z)), rec + 78 + 6*l);
                }
                rupd = c; hav = pos;
            }
        }
        __syncthreads();   // all pass-start reads complete
        if (j0 < n) s[p0] = u0;
        if (j1 < n) s[p1] = u1;
        if (j2 < n) s[p2] = u2;
        if (hav >= 0) s[hav] = rupd;
        __syncthreads();   // writes visible before next pass
    }

    // ---- denormalized core store ----
    for (int j = tid; j < TILE*TILE; j += NT){
        int py = j >> 5, px = j & 31;
        int gy = Y0 + HALO + py, gx = X0 + HALO + px;
        out[sbase + gy*HW + gx] = s[(HALO + py)*SSTR + (HALO + px)] * sc + mn;
    }
}

extern "C" void kernel_launch(void* const* d_in, const int* in_sizes, int n_in,
                              void* d_out, int out_size, void* d_ws, size_t ws_size,
                              hipStream_t stream){
    const float* x     = (const float*)d_in[0];
    const int*   lbl   = (const int*)  d_in[1];
    const int*   index = (const int*)  d_in[2];
    const float* param = (const float*)d_in[3];
    const float* w1    = (const float*)d_in[4];
    const float* b1    = (const float*)d_in[5];
    const float* w2    = (const float*)d_in[6];
    const float* b2    = (const float*)d_in[7];
    float* out = (float*)d_out;
    float* wsf = (float*)d_ws;

    k_minmax<<<256, 256, 0, stream>>>((const float4*)x, wsf);
    k_prep<<<96, 64, 0, stream>>>(index, param, w1, b1, w2, b2, wsf);
    dim3 g(16, 16, 16);
    k_main<<<g, NT, 0, stream>>>(x, lbl, out, wsf);
}